// Round 7
// baseline (95.685 us; speedup 1.0000x reference)
//
#include <hip/hip_runtime.h>
#include <math.h>

// SSIM 1D loss: B=16, C=32, T=48000, window=11, sigma=1.5, zero padding.
// u/v reformulation: u=p+t, v=p-t =>
//   conv(u)=mu1+mu2, conv(v)=mu1-mu2, conv(u^2)=s11+2s12+s22, conv(v^2)=s11-2s12+s22
// => 4 depthwise convs, 2 squares/elem.
//
// R7 = R6 + NON-TEMPORAL input loads (single-variable change).
// R1-R6 all pinned at ~65-95us with identical byte flow: ~100MB HBM + ~97MB L3
// at a combined ~2.9 TB/s -- memory-path-bound on the partially-L3-resident
// stream, not VALU/LDS/vmem-instruction-bound. nt loads bypass L2/L3 retention
// and stream from HBM (~6.3 TB/s ceiling): expect ~197MB FETCH_SIZE and
// dur ~35-48us if the theory holds.
constexpr int T     = 48000;
constexpr int TPB   = 256;
constexpr int OPT   = 8;            // outputs per thread
constexpr int TPROW = T / OPT;      // 6000 threads per row (exact)
constexpr float C1f = 0.0001f;      // 0.01^2
constexpr float C2f = 0.0009f;      // 0.03^2

typedef float f32x4 __attribute__((ext_vector_type(4)));

struct W11 { float w[11]; };

__global__ __launch_bounds__(TPB, 4) void ssim_main(
    const float* __restrict__ pred, const float* __restrict__ targ,
    float* __restrict__ partial, W11 wts)
{
    const int tid = blockIdx.x * TPB + (int)threadIdx.x;   // grid exact: no guard
    const int row = tid / TPROW;                           // magic-mul
    const int pos = (tid - row * TPROW) * OPT;             // first output in row
    const float* pr = pred + (size_t)row * T;
    const float* tr = targ + (size_t)row * T;
    const int g0 = pos - 8;                                // 16B-aligned staged start

    // accumulators: ca=conv(u), cb=conv(v), cc=conv(u^2), cd=conv(v^2)
    float ca[OPT] = {}, cb[OPT] = {}, cc[OPT] = {}, cd[OPT] = {};

    // staged index i in [0,24) = x[g0+i]; output m uses staged [m+3 .. m+13]
    // (tap k = i-3-m in [0,10]); used i-range is [3,20].
    auto consume = [&](int j, const f32x4& a, const f32x4& b) {
        #pragma unroll
        for (int c = 0; c < 4; c++) {
            const int i = 4 * j + c;
            if (i < 3 || i > 20) continue;
            const float u  = a[c] + b[c];
            const float v  = a[c] - b[c];
            const float uu = u * u;
            const float vv = v * v;
            #pragma unroll
            for (int m = 0; m < OPT; m++) {
                const int k = i - 3 - m;
                if (k < 0 || k > 10) continue;
                const float wk = wts.w[k];                 // SGPR, compile-time index
                ca[m] = fmaf(wk, u,  ca[m]);
                cb[m] = fmaf(wk, v,  cb[m]);
                cc[m] = fmaf(wk, uu, cc[m]);
                cd[m] = fmaf(wk, vv, cd[m]);
            }
        }
    };

    if (pos >= 8 && pos + 16 <= T) {                       // interior: straight-line
        const f32x4* P4 = reinterpret_cast<const f32x4*>(pr + g0);
        const f32x4* Q4 = reinterpret_cast<const f32x4*>(tr + g0);
        f32x4 pq[6], tq[6];
        #pragma unroll
        for (int j = 0; j < 6; j++) {                      // MLP: all 12 nt loads in flight
            pq[j] = __builtin_nontemporal_load(P4 + j);
            tq[j] = __builtin_nontemporal_load(Q4 + j);
        }
        #pragma unroll
        for (int j = 0; j < 6; j++) consume(j, pq[j], tq[j]);
    } else {                                               // 2 threads/row: zero-fill OOB
        #pragma unroll
        for (int j = 0; j < 6; j++) {
            const int q = g0 + 4 * j;                      // quad fully in or out (T%4==0)
            f32x4 a = {0.f,0.f,0.f,0.f}, b = {0.f,0.f,0.f,0.f};
            if (q >= 0 && q + 4 <= T) {
                a = *reinterpret_cast<const f32x4*>(pr + q);
                b = *reinterpret_cast<const f32x4*>(tr + q);
            }
            consume(j, a, b);
        }
    }

    // ---- SSIM epilogue; all OPT outputs in-bounds by construction ----
    float qsum = 0.f;
    #pragma unroll
    for (int m = 0; m < OPT; m++) {
        const float aa = ca[m] * ca[m], bb = cb[m] * cb[m];
        const float e  = 0.5f * (aa - bb);                 // 2*mu1*mu2
        const float f  = 0.5f * (aa + bb);                 // mu1^2+mu2^2
        const float t2 = 0.5f * (cc[m] - cd[m]);           // 2*s12
        const float sP = 0.5f * (cc[m] + cd[m]);           // s11+s22
        const float num = (e + C1f) * (t2 - e + C2f);
        const float den = (f + C1f) * (sP - f + C2f);
        qsum += num * __builtin_amdgcn_rcpf(den);          // den >= C1*C2 > 0
    }

    // ---- block reduction -> one partial per block ----
    #pragma unroll
    for (int off = 32; off; off >>= 1) qsum += __shfl_down(qsum, off);
    __shared__ float wsum[TPB / 64];
    if ((threadIdx.x & 63) == 0) wsum[threadIdx.x >> 6] = qsum;
    __syncthreads();
    if (threadIdx.x == 0) {
        float s = 0.f;
        #pragma unroll
        for (int i = 0; i < TPB / 64; i++) s += wsum[i];
        partial[blockIdx.x] = s;
    }
}

__global__ __launch_bounds__(256) void ssim_reduce(
    const float4* __restrict__ partial4, int n4, float* __restrict__ out, float inv_n)
{
    float s = 0.f;
    for (int i = threadIdx.x; i < n4; i += 256) {
        const float4 p = partial4[i];
        s += (p.x + p.y) + (p.z + p.w);
    }
    #pragma unroll
    for (int off = 32; off; off >>= 1) s += __shfl_down(s, off);
    __shared__ float ws[4];
    if ((threadIdx.x & 63) == 0) ws[threadIdx.x >> 6] = s;
    __syncthreads();
    if (threadIdx.x == 0) {
        float t = 0.f;
        #pragma unroll
        for (int i = 0; i < 4; i++) t += ws[i];
        out[0] = 1.f - t * inv_n;                          // mean(1-ssim) = 1 - mean(ssim)
    }
}

extern "C" void kernel_launch(void* const* d_in, const int* in_sizes, int n_in,
                              void* d_out, int out_size, void* d_ws, size_t ws_size,
                              hipStream_t stream)
{
    const float* pred = (const float*)d_in[0];
    const float* targ = (const float*)d_in[1];
    float* out = (float*)d_out;
    float* partial = (float*)d_ws;

    const int n        = in_sizes[0];                      // B*C*T = 24,576,000
    const int rows     = n / T;                            // 512
    const int nthreads = rows * TPROW;                     // 3,072,000 = 12000*256 exactly
    const int blocks   = nthreads / TPB;                   // 12,000 (48 KB of d_ws)

    // Gaussian window computed on host in double (matches numpy), cast to f32.
    W11 wts;
    double g[11], s = 0.0;
    for (int i = 0; i < 11; i++) { g[i] = exp(-((i - 5) * (i - 5)) / 4.5); s += g[i]; }
    for (int i = 0; i < 11; i++) wts.w[i] = (float)(g[i] / s);

    hipLaunchKernelGGL(ssim_main, dim3(blocks), dim3(TPB), 0, stream,
                       pred, targ, partial, wts);
    hipLaunchKernelGGL(ssim_reduce, dim3(1), dim3(256), 0, stream,
                       (const float4*)partial, blocks / 4, out, 1.0f / (float)n);
}

// Round 8
// 49.379 us; speedup vs baseline: 1.9378x; 1.9378x over previous
//
#include <hip/hip_runtime.h>
#include <math.h>

// SSIM 1D loss: B=16, C=32, T=48000, window=11, sigma=1.5, zero padding.
// u/v reformulation: 4 convs (u, v, u^2, v^2) recover all SSIM moments.
//
// R8: perfect coalescing + shuffle halo.
//  - Each thread loads exactly its own 8 elements per stream (2 aligned float4,
//    16B lane stride -> wave-loads are line-dense 1KB transactions, ZERO
//    redundancy). R6's 32B-stride pattern touched 2KB of lines per 1KB used
//    with 3x redundancy -> ~6x line-request rate; that was the memory wall.
//  - +-5 halo via __shfl_up/down of computed u,v (20 shuffles); wave-edge
//    lanes (2/64) patch from global; row edges zero-fill (= lax zero pad).
//  - Tap loop as output-PAIRS with precomputed {g[j],g[j-1]} float2 consts:
//    192 v_pk_fma_f32 candidates instead of 352 scalar FMAs.
//  - __launch_bounds__(256,6): ~2x occupancy vs R6.
constexpr int T     = 48000;
constexpr int TPB   = 256;
constexpr int OPT   = 8;            // outputs per thread
constexpr int TPROW = T / OPT;      // 6000 threads per row (exact)
constexpr float C1f = 0.0001f;      // 0.01^2
constexpr float C2f = 0.0009f;      // 0.03^2

typedef float f32x2 __attribute__((ext_vector_type(2)));
typedef float f32x4 __attribute__((ext_vector_type(4)));

struct WP { f32x2 wp[12]; };        // wp[j] = {g[j], g[j-1]}, 0 outside [0,10]

__global__ __launch_bounds__(TPB, 6) void ssim_main(
    const float* __restrict__ pred, const float* __restrict__ targ,
    float* __restrict__ partial, WP wts)
{
    const int tid  = blockIdx.x * TPB + (int)threadIdx.x;   // grid exact
    const int lane = threadIdx.x & 63;
    const int rp   = (tid % TPROW) * OPT;                   // pos within row
    const size_t base = (size_t)tid * OPT;                  // flat first output

    // ---- own data: exactly x[base .. base+7], unit-stride coalesced ----
    const f32x4* P4 = reinterpret_cast<const f32x4*>(pred + base);
    const f32x4* Q4 = reinterpret_cast<const f32x4*>(targ + base);
    const f32x4 p0 = P4[0], p1 = P4[1];
    const f32x4 q0 = Q4[0], q1 = Q4[1];
    const f32x4 u0 = p0 + q0, u1 = p1 + q1;
    const f32x4 v0 = p0 - q0, v1 = p1 - q1;

    // window index w=0..17 <-> x[base-5+w]; own j=0..7 at w=5+j
    float U[18], V[18];
    U[5]=u0.x; U[6]=u0.y; U[7]=u0.z; U[8]=u0.w; U[9]=u1.x; U[10]=u1.y; U[11]=u1.z; U[12]=u1.w;
    V[5]=v0.x; V[6]=v0.y; V[7]=v0.z; V[8]=v0.w; V[9]=v1.x; V[10]=v1.y; V[11]=v1.z; V[12]=v1.w;

    // ---- halo via shuffles (all lanes active here) ----
    #pragma unroll
    for (int j = 0; j < 5; j++) {                 // left: prev thread's w=8+j
        U[j] = __shfl_up(U[8 + j], 1);
        V[j] = __shfl_up(V[8 + j], 1);
    }
    #pragma unroll
    for (int j = 0; j < 5; j++) {                 // right: next thread's w=5+j
        U[13 + j] = __shfl_down(U[5 + j], 1);
        V[13 + j] = __shfl_down(V[5 + j], 1);
    }

    const bool leftEdge  = (rp == 0);
    const bool rightEdge = (rp == T - OPT);

    // wave-edge lanes: shuffle source invalid -> patch from global
    if (lane == 0 && !leftEdge) {                 // x[base-8 .. base-1], use [3..7]
        const f32x4 a0 = reinterpret_cast<const f32x4*>(pred + base - 8)[0];
        const f32x4 a1 = reinterpret_cast<const f32x4*>(pred + base - 8)[1];
        const f32x4 b0 = reinterpret_cast<const f32x4*>(targ + base - 8)[0];
        const f32x4 b1 = reinterpret_cast<const f32x4*>(targ + base - 8)[1];
        U[0]=a0.w+b0.w; V[0]=a0.w-b0.w;
        U[1]=a1.x+b1.x; V[1]=a1.x-b1.x;
        U[2]=a1.y+b1.y; V[2]=a1.y-b1.y;
        U[3]=a1.z+b1.z; V[3]=a1.z-b1.z;
        U[4]=a1.w+b1.w; V[4]=a1.w-b1.w;
    }
    if (lane == 63 && !rightEdge) {               // x[base+8 .. base+15], use [0..4]
        const f32x4 c0 = reinterpret_cast<const f32x4*>(pred + base + 8)[0];
        const f32x4 c1 = reinterpret_cast<const f32x4*>(pred + base + 8)[1];
        const f32x4 d0 = reinterpret_cast<const f32x4*>(targ + base + 8)[0];
        const f32x4 d1 = reinterpret_cast<const f32x4*>(targ + base + 8)[1];
        U[13]=c0.x+d0.x; V[13]=c0.x-d0.x;
        U[14]=c0.y+d0.y; V[14]=c0.y-d0.y;
        U[15]=c0.z+d0.z; V[15]=c0.z-d0.z;
        U[16]=c0.w+d0.w; V[16]=c0.w-d0.w;
        U[17]=c1.x+d1.x; V[17]=c1.x-d1.x;
    }
    if (leftEdge) {                               // zero pad (row start)
        #pragma unroll
        for (int j = 0; j < 5; j++) { U[j] = 0.f; V[j] = 0.f; }
    }
    if (rightEdge) {                              // zero pad (row end)
        #pragma unroll
        for (int j = 13; j < 18; j++) { U[j] = 0.f; V[j] = 0.f; }
    }

    // ---- consume: window w contributes weight g[w-m] to output m ----
    // output pair (2p,2p+1): j = w-2p, weights wp[j] = {g[j], g[j-1]}, j in [0,11]
    f32x2 cA[4] = {}, cB[4] = {}, cC[4] = {}, cD[4] = {};
    #pragma unroll
    for (int w = 0; w < 18; w++) {
        const float u  = U[w], v = V[w];
        const float uu = u * u, vv = v * v;
        #pragma unroll
        for (int p = 0; p < 4; p++) {
            const int j = w - 2 * p;
            if (j < 0 || j > 11) continue;
            const f32x2 wp = wts.wp[j];
            cA[p] += u  * wp;                     // -> v_pk_fma_f32 candidates
            cB[p] += v  * wp;
            cC[p] += uu * wp;
            cD[p] += vv * wp;
        }
    }

    // ---- packed SSIM epilogue ----
    float qsum = 0.f;
    #pragma unroll
    for (int p = 0; p < 4; p++) {
        const f32x2 aa = cA[p] * cA[p], bb = cB[p] * cB[p];
        const f32x2 e   = 0.5f * (aa - bb);       // 2*mu1*mu2
        const f32x2 f2  = 0.5f * (aa + bb);       // mu1^2+mu2^2
        const f32x2 t2  = 0.5f * (cC[p] - cD[p]); // 2*s12
        const f32x2 sP  = 0.5f * (cC[p] + cD[p]); // s11+s22
        const f32x2 num = (e + C1f) * (t2 - e + C2f);
        const f32x2 den = (f2 + C1f) * (sP - f2 + C2f);
        qsum += num.x * __builtin_amdgcn_rcpf(den.x);   // den >= C1*C2 > 0
        qsum += num.y * __builtin_amdgcn_rcpf(den.y);
    }

    // ---- block reduction -> one partial per block ----
    #pragma unroll
    for (int off = 32; off; off >>= 1) qsum += __shfl_down(qsum, off);
    __shared__ float wsum[TPB / 64];
    if ((threadIdx.x & 63) == 0) wsum[threadIdx.x >> 6] = qsum;
    __syncthreads();
    if (threadIdx.x == 0) {
        float s = 0.f;
        #pragma unroll
        for (int i = 0; i < TPB / 64; i++) s += wsum[i];
        partial[blockIdx.x] = s;
    }
}

__global__ __launch_bounds__(256) void ssim_reduce(
    const float4* __restrict__ partial4, int n4, float* __restrict__ out, float inv_n)
{
    float s = 0.f;
    for (int i = threadIdx.x; i < n4; i += 256) {
        const float4 p = partial4[i];
        s += (p.x + p.y) + (p.z + p.w);
    }
    #pragma unroll
    for (int off = 32; off; off >>= 1) s += __shfl_down(s, off);
    __shared__ float ws[4];
    if ((threadIdx.x & 63) == 0) ws[threadIdx.x >> 6] = s;
    __syncthreads();
    if (threadIdx.x == 0) {
        float t = 0.f;
        #pragma unroll
        for (int i = 0; i < 4; i++) t += ws[i];
        out[0] = 1.f - t * inv_n;                 // mean(1-ssim) = 1 - mean(ssim)
    }
}

extern "C" void kernel_launch(void* const* d_in, const int* in_sizes, int n_in,
                              void* d_out, int out_size, void* d_ws, size_t ws_size,
                              hipStream_t stream)
{
    const float* pred = (const float*)d_in[0];
    const float* targ = (const float*)d_in[1];
    float* out = (float*)d_out;
    float* partial = (float*)d_ws;

    const int n      = in_sizes[0];               // B*C*T = 24,576,000
    const int blocks = n / OPT / TPB;             // 12,000 exactly (48 KB d_ws)

    // Gaussian window on host in double (matches numpy), then adjacent pairs.
    double g[11], s = 0.0;
    for (int i = 0; i < 11; i++) { g[i] = exp(-((i - 5) * (i - 5)) / 4.5); s += g[i]; }
    float gw[11];
    for (int i = 0; i < 11; i++) gw[i] = (float)(g[i] / s);
    WP wts;
    for (int j = 0; j < 12; j++) {
        wts.wp[j].x = (j <= 10) ? gw[j] : 0.f;
        wts.wp[j].y = (j >= 1) ? gw[j - 1] : 0.f;
    }

    hipLaunchKernelGGL(ssim_main, dim3(blocks), dim3(TPB), 0, stream,
                       pred, targ, partial, wts);
    hipLaunchKernelGGL(ssim_reduce, dim3(1), dim3(256), 0, stream,
                       (const float4*)partial, blocks / 4, out, 1.0f / (float)n);
}